// Round 1
// baseline (345.266 us; speedup 1.0000x reference)
//
#include <hip/hip_runtime.h>
#include <stdint.h>

typedef int int32x4 __attribute__((ext_vector_type(4)));

#define HW_    3136          // 56*56
#define CHW_   802816        // 256*3136
#define HP_    58
#define WP_    58
#define QXP_BYTES (32ull*58*58*256)   // 27,557,888 padded NHWC int8 activations
#define QWT_BYTES (9ull*256*256)      // 589,824   [kk][o][c] int8 weights

__device__ __forceinline__ signed char quant8(float v, float s) {
    float t = v * s;
    t = fmaxf(t, -128.0f);   // clip FIRST (matches reference: round(clip(...)))
    t = fminf(t, 127.0f);
    return (signed char)(int)rintf(t);   // v_rndne: half-to-even, matches jnp.round
}

// ---------------- weight quantize: w[o][c][kh][kw] -> qwT[kk][o][c] ----------------
__global__ __launch_bounds__(256) void quant_w_kernel(
    const float* __restrict__ wgt, const float* __restrict__ sw,
    signed char* __restrict__ qwT)
{
    int u = blockIdx.x * 256 + threadIdx.x;      // 147456 uchar4 chunks
    int kk  = u >> 14;                            // / 16384
    int rem = u & 16383;
    int o   = rem >> 6;
    int c0  = (rem & 63) << 2;
    float s = sw[o];
    char4 q;
    q.x = quant8(wgt[(o*256 + c0+0)*9 + kk], s);
    q.y = quant8(wgt[(o*256 + c0+1)*9 + kk], s);
    q.z = quant8(wgt[(o*256 + c0+2)*9 + kk], s);
    q.w = quant8(wgt[(o*256 + c0+3)*9 + kk], s);
    *(char4*)(qwT + (size_t)u*4) = q;
}

// ---------------- activation quantize: x NCHW fp32 -> qxp padded NHWC int8 ----------------
// one block per (b,h); LDS transpose [c][w] (row pad 68 bytes)
__global__ __launch_bounds__(256) void quant_x_kernel(
    const float* __restrict__ x, const float* __restrict__ sx,
    signed char* __restrict__ qxp)
{
    __shared__ signed char tile[256*68];
    const int tid = threadIdx.x;
    const int bh = blockIdx.x;
    const int b = bh / 56, h = bh % 56;
    const float s = sx[0];
    const size_t xbase = (size_t)b*CHW_ + (size_t)h*56;
    #pragma unroll
    for (int it = 0; it < 14; ++it) {
        int v = tid + it*256;                 // 3584 float4 chunks: c-major
        int c = v / 14;
        int j = v - c*14;
        float4 f = *(const float4*)(x + xbase + (size_t)c*HW_ + 4*j);
        char4 q;
        q.x = quant8(f.x, s); q.y = quant8(f.y, s);
        q.z = quant8(f.z, s); q.w = quant8(f.w, s);
        *(char4*)&tile[c*68 + 4*j] = q;
    }
    __syncthreads();
    const size_t obase = ((size_t)(b*HP_ + h + 1)*WP_ + 1)*256;   // +1,+1 halo shift
    #pragma unroll
    for (int it = 0; it < 14; ++it) {
        int u = tid + it*256;                 // 3584 uchar4 out chunks: w-major
        int w  = u >> 6;
        int c4 = (u & 63) << 2;
        char4 q;
        q.x = tile[(c4+0)*68 + w];
        q.y = tile[(c4+1)*68 + w];
        q.z = tile[(c4+2)*68 + w];
        q.w = tile[(c4+3)*68 + w];
        *(char4*)(qxp + obase + (size_t)w*256 + c4) = q;
    }
}

// ---------------- int8 implicit-GEMM conv ----------------
// A = weights (M=o), B = pixels (N=b*h*w), K = (kk,c) = 2304
// block tile 128x128, 4 waves of 64x64, MFMA i32_16x16x64_i8, BK=64
__device__ __forceinline__ void load16_lds(const void* g, void* l) {
    __builtin_amdgcn_global_load_lds(
        (const unsigned int*)g,
        reinterpret_cast<__attribute__((address_space(3))) unsigned int*>(
            reinterpret_cast<uintptr_t>(l)),
        16, 0, 0);
}

__global__ __launch_bounds__(256) void conv_kernel(
    const signed char* __restrict__ qxp, const signed char* __restrict__ qwT,
    const float* __restrict__ sw, const float* __restrict__ bias,
    const float* __restrict__ sx, float* __restrict__ out)
{
    // LDS layout per tile: [kc(4)][row(128)][16B]  (kc = 16B chunk of the 64B K-step)
    __shared__ __align__(16) signed char ldsA[8192];
    __shared__ __align__(16) signed char ldsB[8192];
    __shared__ float invS[128];
    __shared__ float biasS[128];

    const int tid  = threadIdx.x;
    const int wave = tid >> 6;
    const int lane = tid & 63;
    const int s0 = blockIdx.x * 128;   // spatial tile
    const int o0 = blockIdx.y * 128;   // out-channel tile

    if (tid < 128) {
        float s = sw[o0 + tid];
        invS[tid]  = 1.0f / (s * sx[0]);
        biasS[tid] = bias[o0 + tid];
    }

    // staging: wave stages kc=wave; lane covers rows {lane, lane+64}
    const unsigned sp0 = (unsigned)(s0 + lane);
    const unsigned sp1 = (unsigned)(s0 + 64 + lane);
    unsigned b0 = sp0 / HW_, r0 = sp0 - b0*HW_;
    unsigned b1 = sp1 / HW_, r1 = sp1 - b1*HW_;
    unsigned h0 = r0 / 56,   w0 = r0 - h0*56;
    unsigned h1 = r1 / 56,   w1 = r1 - h1*56;
    const size_t pixBase0 = (((size_t)b0*HP_ + h0)*WP_ + w0)*256;  // padded coords: +kh,+kw added per step
    const size_t pixBase1 = (((size_t)b1*HP_ + h1)*WP_ + w1)*256;
    const size_t aBase0 = (size_t)(o0 + lane)*256;
    const size_t aBase1 = (size_t)(o0 + 64 + lane)*256;

    int32x4 acc[4][4];
    #pragma unroll
    for (int i = 0; i < 4; ++i)
        #pragma unroll
        for (int j = 0; j < 4; ++j)
            acc[i][j] = (int32x4){0,0,0,0};

    const int wo = (wave & 1) << 6;          // o half
    const int wn = (wave >> 1) << 6;         // spatial half
    const int kcOff = (lane >> 4) << 11;     // kc*2048
    const int rowB = (wn + (lane & 15)) << 4;
    const int rowA = (wo + (lane & 15)) << 4;
    signed char* ldsBw = ldsB + (wave << 11);
    signed char* ldsAw = ldsA + (wave << 11);
    const int wv16 = wave << 4;

    for (int kk = 0; kk < 9; ++kk) {
        const size_t stepB = (size_t)((kk/3)*WP_ + (kk%3))*256;
        const size_t stepA = (size_t)kk << 16;
        #pragma unroll
        for (int c0 = 0; c0 < 256; c0 += 64) {
            load16_lds(qxp + pixBase0 + stepB + c0 + wv16, ldsBw);
            load16_lds(qxp + pixBase1 + stepB + c0 + wv16, ldsBw + 1024);
            load16_lds(qwT + aBase0  + stepA + c0 + wv16, ldsAw);
            load16_lds(qwT + aBase1  + stepA + c0 + wv16, ldsAw + 1024);
            __syncthreads();   // compiler emits vmcnt(0) drain before s_barrier

            int32x4 af[4], bf[4];
            #pragma unroll
            for (int t = 0; t < 4; ++t) {
                af[t] = *(const int32x4*)&ldsA[kcOff + rowA + (t << 8)];
                bf[t] = *(const int32x4*)&ldsB[kcOff + rowB + (t << 8)];
            }
            #pragma unroll
            for (int mt = 0; mt < 4; ++mt)
                #pragma unroll
                for (int nt = 0; nt < 4; ++nt)
                    acc[mt][nt] = __builtin_amdgcn_mfma_i32_16x16x64_i8(
                        af[mt], bf[nt], acc[mt][nt], 0, 0, 0);
            __syncthreads();
        }
    }

    // epilogue: D[m=o][n=sp], col = lane&15 (spatial -> coalesced), row = quad*4 + r
    const int quad = lane >> 4;
    #pragma unroll
    for (int nt = 0; nt < 4; ++nt) {
        unsigned sp = (unsigned)(s0 + wn + nt*16 + (lane & 15));
        unsigned b  = sp / HW_;
        unsigned pos = sp - b*HW_;
        float* outN = out + (size_t)b*CHW_ + pos + (size_t)o0*HW_;
        #pragma unroll
        for (int mt = 0; mt < 4; ++mt) {
            const int ob = wo + (mt << 4) + (quad << 2);
            #pragma unroll
            for (int r = 0; r < 4; ++r) {
                const int ol = ob + r;
                float v = fmaf((float)acc[mt][nt][r], invS[ol], biasS[ol]);
                outN[(size_t)ol * HW_] = v;
            }
        }
    }
}

extern "C" void kernel_launch(void* const* d_in, const int* in_sizes, int n_in,
                              void* d_out, int out_size, void* d_ws, size_t ws_size,
                              hipStream_t stream)
{
    (void)in_sizes; (void)n_in; (void)out_size; (void)ws_size;
    const float* x    = (const float*)d_in[0];
    const float* wgt  = (const float*)d_in[1];
    const float* bias = (const float*)d_in[2];
    const float* sw   = (const float*)d_in[3];
    const float* sx   = (const float*)d_in[4];
    float* out = (float*)d_out;

    signed char* qxp = (signed char*)d_ws;            // padded NHWC int8
    signed char* qwT = qxp + QXP_BYTES;               // [kk][o][c] int8

    hipMemsetAsync(qxp, 0, QXP_BYTES, stream);        // zero halo (and interior, overwritten)
    quant_w_kernel<<<576, 256, 0, stream>>>(wgt, sw, qwT);
    quant_x_kernel<<<1792, 256, 0, stream>>>(x, sx, qxp);
    conv_kernel<<<dim3(784, 2), 256, 0, stream>>>(qxp, qwT, sw, bias, sx, out);
}

// Round 2
// 304.900 us; speedup vs baseline: 1.1324x; 1.1324x over previous
//
#include <hip/hip_runtime.h>
#include <stdint.h>

typedef int int32x4 __attribute__((ext_vector_type(4)));

#define HW_        3136          // 56*56
#define CHW_       802816        // 256*3136
#define HP_        58
#define WP_        58
#define PLANE_PIX  107648ull     // 32*58*58 pixels per 16-channel plane
#define PLANE_B    (PLANE_PIX*16)        // 1,722,368 B
#define QXP_BYTES  (16ull*PLANE_B)       // 27,557,888 B : [cq][b][hp][wp][16]
#define QWT_BYTES  (9ull*16*256*16)      // 589,824  B : [kk][cq][o][16]

__device__ __forceinline__ signed char quant8(float v, float s) {
    float t = v * s;
    t = fmaxf(t, -128.0f);                 // clip FIRST (round(clip(...)))
    t = fminf(t, 127.0f);
    return (signed char)(int)rintf(t);     // half-to-even == jnp.round
}

// ---------------- halo zero: pad pixels of all 16 planes ----------------
__global__ __launch_bounds__(256) void halo_zero_kernel(signed char* __restrict__ qxp2) {
    const int b = blockIdx.x, hp = blockIdx.y, tid = threadIdx.x;
    const int32x4 z = {0,0,0,0};
    const size_t rowpix = (size_t)(b*HP_ + hp)*WP_;
    if (hp == 0 || hp == HP_-1) {
        for (int q = tid; q < 16*WP_; q += 256) {       // 928 chunks
            int cq = q / WP_, wp = q - cq*WP_;
            *(int32x4*)(qxp2 + (cq*PLANE_PIX + rowpix + wp)*16) = z;
        }
    } else if (tid < 32) {
        int cq = tid >> 1, wp = (tid & 1) * (WP_-1);
        *(int32x4*)(qxp2 + (cq*PLANE_PIX + rowpix + wp)*16) = z;
    }
}

// ---------------- weight quantize: w[o][c][3][3] -> qwT2[kk][cq][o][16] ----------------
__global__ __launch_bounds__(256) void quant_w_kernel(
    const float* __restrict__ wgt, const float* __restrict__ sw,
    signed char* __restrict__ qwT2)
{
    __shared__ __align__(16) signed char lw[9*272];
    const int o = blockIdx.x, c = threadIdx.x;
    const float s = sw[o];
    const float* wp = wgt + ((size_t)o*256 + c)*9;
    #pragma unroll
    for (int kk = 0; kk < 9; ++kk)
        lw[kk*272 + c] = quant8(wp[kk], s);
    __syncthreads();
    if (c < 144) {
        int kk = c / 16, cq = c - kk*16;
        int32x4 v = *(const int32x4*)&lw[kk*272 + cq*16];
        *(int32x4*)(qwT2 + ((size_t)(kk*16 + cq)*256 + o)*16) = v;
    }
}

// ---------------- activation quantize: x NCHW fp32 -> qxp2[cq][b][hp][wp][16] ----------------
__global__ __launch_bounds__(256) void quant_x_kernel(
    const float* __restrict__ x, const float* __restrict__ sx,
    signed char* __restrict__ qxp2)
{
    __shared__ __align__(16) signed char tile[56*272];   // [w][c] row pad 272
    const int tid = threadIdx.x;
    const int bh = blockIdx.x;
    const int b = bh / 56, h = bh % 56;
    const float s = sx[0];
    const size_t xbase = (size_t)b*CHW_ + (size_t)h*56;
    #pragma unroll
    for (int it = 0; it < 14; ++it) {
        int v = tid + it*256;                 // 3584 float4: c-major
        int c = v / 14;
        int j = v - c*14;
        float4 f = *(const float4*)(x + xbase + (size_t)c*HW_ + 4*j);
        tile[(4*j+0)*272 + c] = quant8(f.x, s);
        tile[(4*j+1)*272 + c] = quant8(f.y, s);
        tile[(4*j+2)*272 + c] = quant8(f.z, s);
        tile[(4*j+3)*272 + c] = quant8(f.w, s);
    }
    __syncthreads();
    const size_t pbase = (size_t)(b*HP_ + h + 1)*WP_ + 1;   // padded (h+1, w+1)
    #pragma unroll
    for (int it = 0; it < 4; ++it) {
        int q = tid + it*256;                 // 896 chunks: cq-major, w fastest
        if (q < 896) {
            int cq = q / 56, w = q - cq*56;
            int32x4 v = *(const int32x4*)&tile[w*272 + cq*16];
            *(int32x4*)(qxp2 + (cq*PLANE_PIX + pbase + w)*16) = v;
        }
    }
}

// ---------------- int8 implicit-GEMM conv ----------------
// A = qwT2 (M=o), B = qxp2 (N=pixels), K = 9*256. Tile 128x128, BK=128.
// LDS [kc(8)][row(128)][16B]; staging 1KB contiguous per global_load_lds.
__device__ __forceinline__ void load16_lds(const void* g, void* l) {
    __builtin_amdgcn_global_load_lds(
        (const unsigned int*)g,
        reinterpret_cast<__attribute__((address_space(3))) unsigned int*>(
            reinterpret_cast<uintptr_t>(l)),
        16, 0, 0);
}

__global__ __launch_bounds__(256, 4) void conv_kernel(
    const signed char* __restrict__ qxp2, const signed char* __restrict__ qwT2,
    const float* __restrict__ sw, const float* __restrict__ bias,
    const float* __restrict__ sx, float* __restrict__ out)
{
    __shared__ __align__(16) signed char ldsA[16384];   // [kc][row][16]
    __shared__ __align__(16) signed char ldsB[16384];
    __shared__ float invS[128];
    __shared__ float biasS[128];

    const int tid  = threadIdx.x;
    const int wave = tid >> 6;
    const int lane = tid & 63;
    const int quad = lane >> 4;
    const int l15  = lane & 15;
    const int s0 = blockIdx.x * 128;   // spatial tile
    const int o0 = blockIdx.y * 128;   // out-channel tile

    if (tid < 128) {
        float s = sw[o0 + tid];
        invS[tid]  = 1.0f / (s * sx[0]);
        biasS[tid] = bias[o0 + tid];
    }

    // per-lane pixel indices (padded space) for B rows {lane, lane+64}
    const unsigned sp0 = (unsigned)(s0 + lane);
    const unsigned sp1 = (unsigned)(s0 + 64 + lane);
    unsigned b0 = sp0 / HW_, r0 = sp0 - b0*HW_;
    unsigned b1 = sp1 / HW_, r1 = sp1 - b1*HW_;
    unsigned h0 = r0 / 56,   w0 = r0 - h0*56;
    unsigned h1 = r1 / 56,   w1 = r1 - h1*56;
    const size_t bOff0 = ((size_t)(b0*HP_ + h0)*WP_ + w0)*16;   // + kshift per step
    const size_t bOff1 = ((size_t)(b1*HP_ + h1)*WP_ + w1)*16;
    const size_t aOff0 = (size_t)(o0 + lane)*16;                // rows 0..63
    const size_t aOff1 = aOff0 + 1024;                          // rows 64..127

    int32x4 acc[4][4];
    #pragma unroll
    for (int i = 0; i < 4; ++i)
        #pragma unroll
        for (int j = 0; j < 4; ++j)
            acc[i][j] = (int32x4){0,0,0,0};

    const int wo = (wave & 1) << 6;          // o half of wave tile
    const int wn = (wave >> 1) << 6;         // spatial half

    for (int kk = 0; kk < 9; ++kk) {
        const size_t kshift = (size_t)((kk/3)*WP_ + (kk%3))*16;   // pixel shift bytes
        const size_t aKK = (size_t)kk*16*4096;
        #pragma unroll
        for (int hf = 0; hf < 2; ++hf) {            // K halves: cq0 = 0, 8
            const int cq0 = hf*8;
            #pragma unroll
            for (int t = 0; t < 2; ++t) {
                const int kc = 2*wave + t;          // this wave's LDS chunks
                const int cq = cq0 + kc;
                const signed char* aG = qwT2 + aKK + (size_t)cq*4096;
                load16_lds(aG + aOff0, ldsA + kc*2048);
                load16_lds(aG + aOff1, ldsA + kc*2048 + 1024);
                const signed char* bG = qxp2 + (size_t)cq*PLANE_B + kshift;
                load16_lds(bG + bOff0, ldsB + kc*2048);
                load16_lds(bG + bOff1, ldsB + kc*2048 + 1024);
            }
            __syncthreads();
            #pragma unroll
            for (int ks = 0; ks < 2; ++ks) {
                const int ck = (ks*4 + quad)*2048;
                int32x4 af[4], bf[4];
                #pragma unroll
                for (int t = 0; t < 4; ++t) {
                    af[t] = *(const int32x4*)&ldsA[ck + (wo + t*16 + l15)*16];
                    bf[t] = *(const int32x4*)&ldsB[ck + (wn + t*16 + l15)*16];
                }
                #pragma unroll
                for (int mt = 0; mt < 4; ++mt)
                    #pragma unroll
                    for (int nt = 0; nt < 4; ++nt)
                        acc[mt][nt] = __builtin_amdgcn_mfma_i32_16x16x64_i8(
                            af[mt], bf[nt], acc[mt][nt], 0, 0, 0);
            }
            __syncthreads();
        }
    }

    // epilogue: D col = lane&15 (spatial, coalesced), row = quad*4 + r
    #pragma unroll
    for (int nt = 0; nt < 4; ++nt) {
        unsigned sp = (unsigned)(s0 + wn + nt*16 + l15);
        unsigned b  = sp / HW_;
        unsigned pos = sp - b*HW_;
        float* outN = out + (size_t)b*CHW_ + pos + (size_t)o0*HW_;
        #pragma unroll
        for (int mt = 0; mt < 4; ++mt) {
            const int ob = wo + (mt << 4) + (quad << 2);
            #pragma unroll
            for (int r = 0; r < 4; ++r) {
                const int ol = ob + r;
                outN[(size_t)ol * HW_] = fmaf((float)acc[mt][nt][r], invS[ol], biasS[ol]);
            }
        }
    }
}

extern "C" void kernel_launch(void* const* d_in, const int* in_sizes, int n_in,
                              void* d_out, int out_size, void* d_ws, size_t ws_size,
                              hipStream_t stream)
{
    (void)in_sizes; (void)n_in; (void)out_size; (void)ws_size;
    const float* x    = (const float*)d_in[0];
    const float* wgt  = (const float*)d_in[1];
    const float* bias = (const float*)d_in[2];
    const float* sw   = (const float*)d_in[3];
    const float* sx   = (const float*)d_in[4];
    float* out = (float*)d_out;

    signed char* qxp2 = (signed char*)d_ws;           // [cq][b][hp][wp][16]
    signed char* qwT2 = qxp2 + QXP_BYTES;             // [kk][cq][o][16]

    halo_zero_kernel<<<dim3(32, 58), 256, 0, stream>>>(qxp2);
    quant_w_kernel<<<256, 256, 0, stream>>>(wgt, sw, qwT2);
    quant_x_kernel<<<1792, 256, 0, stream>>>(x, sx, qxp2);
    conv_kernel<<<dim3(784, 2), 256, 0, stream>>>(qxp2, qwT2, sw, bias, sx, out);
}

// Round 3
// 282.909 us; speedup vs baseline: 1.2204x; 1.0777x over previous
//
#include <hip/hip_runtime.h>
#include <stdint.h>

typedef int int32x4 __attribute__((ext_vector_type(4)));

#define HW_        3136          // 56*56
#define CHW_       802816        // 256*3136
#define HP_        58
#define WP_        58
#define PLANE_PIX  107648ull     // 32*58*58 pixels per 16-channel plane
#define PLANE_B    (PLANE_PIX*16)        // 1,722,368 B
#define QXP_BYTES  (16ull*PLANE_B)       // 27,557,888 B : [cq][b][hp][wp][16]
#define QWT_BYTES  (9ull*16*256*16)      // 589,824  B : [kk][cq][o][16]

__device__ __forceinline__ signed char quant8(float v, float s) {
    float t = v * s;
    t = fmaxf(t, -128.0f);                 // clip FIRST (round(clip(...)))
    t = fminf(t, 127.0f);
    return (signed char)(int)rintf(t);     // half-to-even == jnp.round
}

// ---------------- halo rows: zero padded rows hp=0 and hp=57 (all b, cq) ----------------
__global__ __launch_bounds__(256) void halo_rows_kernel(signed char* __restrict__ qxp2) {
    int idx = blockIdx.x*256 + threadIdx.x;     // 16*32*2*58 = 59392 chunks
    if (idx < 16*32*2*58) {
        int cq = idx / (32*2*58);
        int r  = idx % (32*2*58);
        int b  = r / (2*58);
        int t  = r % (2*58);
        int hp = (t / 58) * (HP_-1);
        int wp = t % 58;
        *(int32x4*)(qxp2 + ((size_t)cq*PLANE_PIX + (size_t)(b*HP_+hp)*WP_ + wp)*16)
            = (int32x4){0,0,0,0};
    }
}

// ---------------- weight quantize: w[o][c][3][3] -> qwT2[kk][cq][o][16] ----------------
__global__ __launch_bounds__(256) void quant_w_kernel(
    const float* __restrict__ wgt, const float* __restrict__ sw,
    signed char* __restrict__ qwT2)
{
    __shared__ __align__(16) signed char lw[9*272];
    const int o = blockIdx.x, c = threadIdx.x;
    const float s = sw[o];
    const float* wp = wgt + ((size_t)o*256 + c)*9;
    #pragma unroll
    for (int kk = 0; kk < 9; ++kk)
        lw[kk*272 + c] = quant8(wp[kk], s);
    __syncthreads();
    if (c < 144) {
        int kk = c / 16, cq = c - kk*16;
        int32x4 v = *(const int32x4*)&lw[kk*272 + cq*16];
        *(int32x4*)(qwT2 + ((size_t)(kk*16 + cq)*256 + o)*16) = v;
    }
}

// ---------------- activation quantize: x NCHW fp32 -> qxp2[cq][b][hp][wp][16] ----------------
// LDS-free: thread <-> (cq-group, w). Coalesced scalar reads, contiguous 16B stores.
__global__ __launch_bounds__(256) void quant_x_kernel(
    const float* __restrict__ x, const float* __restrict__ sx,
    signed char* __restrict__ qxp2)
{
    const int tid = threadIdx.x;
    const int bh = blockIdx.x;                // 32*56
    const int b = bh / 56, h = bh % 56;
    const float s = sx[0];
    if (tid < 224) {
        const int w  = tid % 56;
        const int cg = tid / 56;              // 0..3 -> cq = cg*4+k
        const size_t xrow = (size_t)b*CHW_ + (size_t)h*56 + w;
        const size_t pb = ((size_t)(b*HP_ + h + 1)*WP_ + 1 + w)*16;
        #pragma unroll
        for (int k = 0; k < 4; ++k) {
            const int cq = cg*4 + k;
            const float* xp = x + xrow + (size_t)(cq*16)*HW_;
            int pk[4];
            #pragma unroll
            for (int g = 0; g < 4; ++g) {
                int b0 = (unsigned char)quant8(xp[(size_t)(4*g+0)*HW_], s);
                int b1 = (unsigned char)quant8(xp[(size_t)(4*g+1)*HW_], s);
                int b2 = (unsigned char)quant8(xp[(size_t)(4*g+2)*HW_], s);
                int b3 = (unsigned char)quant8(xp[(size_t)(4*g+3)*HW_], s);
                pk[g] = b0 | (b1 << 8) | (b2 << 16) | (b3 << 24);
            }
            *(int32x4*)(qxp2 + (size_t)cq*PLANE_B + pb) = (int32x4){pk[0],pk[1],pk[2],pk[3]};
        }
    } else {
        // w-halo of this padded row: w = 0 and 57, all 16 cq
        int t2 = tid - 224;                   // 0..31
        int cq = t2 >> 1, wp = (t2 & 1) * (WP_-1);
        const size_t rowpix = (size_t)(b*HP_ + h + 1)*WP_;
        *(int32x4*)(qxp2 + ((size_t)cq*PLANE_PIX + rowpix + wp)*16) = (int32x4){0,0,0,0};
    }
}

// ---------------- int8 implicit-GEMM conv ----------------
// A = qwT2 (M=o), B = qxp2 (N=pixels), K = 9*256. Tile 128x128, BK=128.
// LDS [kc(8)][row(128)][16B]; staging 1KB contiguous per global_load_lds.
__device__ __forceinline__ void load16_lds(const void* g, void* l) {
    __builtin_amdgcn_global_load_lds(
        (const unsigned int*)g,
        reinterpret_cast<__attribute__((address_space(3))) unsigned int*>(
            reinterpret_cast<uintptr_t>(l)),
        16, 0, 0);
}

__global__ __launch_bounds__(256, 4) void conv_kernel(
    const signed char* __restrict__ qxp2, const signed char* __restrict__ qwT2,
    const float* __restrict__ sw, const float* __restrict__ bias,
    const float* __restrict__ sx, float* __restrict__ out)
{
    __shared__ __align__(16) signed char smem[33792];   // K-loop: ldsA+ldsB; epilogue: lt[64][132]f
    __shared__ float invS[128];
    __shared__ float biasS[128];
    signed char* ldsA = smem;            // [kc][row][16]
    signed char* ldsB = smem + 16384;

    const int tid  = threadIdx.x;
    const int wave = tid >> 6;
    const int lane = tid & 63;
    const int quad = lane >> 4;
    const int l15  = lane & 15;
    const int s0 = blockIdx.x * 128;   // spatial tile
    const int o0 = blockIdx.y * 128;   // out-channel tile

    if (tid < 128) {
        float s = sw[o0 + tid];
        invS[tid]  = 1.0f / (s * sx[0]);
        biasS[tid] = bias[o0 + tid];
    }

    // per-lane pixel indices (padded space) for B rows {lane, lane+64}
    const unsigned sp0 = (unsigned)(s0 + lane);
    const unsigned sp1 = (unsigned)(s0 + 64 + lane);
    unsigned b0 = sp0 / HW_, r0 = sp0 - b0*HW_;
    unsigned b1 = sp1 / HW_, r1 = sp1 - b1*HW_;
    unsigned h0 = r0 / 56,   w0 = r0 - h0*56;
    unsigned h1 = r1 / 56,   w1 = r1 - h1*56;
    const size_t bOff0 = ((size_t)(b0*HP_ + h0)*WP_ + w0)*16;   // + kshift per step
    const size_t bOff1 = ((size_t)(b1*HP_ + h1)*WP_ + w1)*16;
    const size_t aOff0 = (size_t)(o0 + lane)*16;                // rows 0..63
    const size_t aOff1 = aOff0 + 1024;                          // rows 64..127

    int32x4 acc[4][4];
    #pragma unroll
    for (int i = 0; i < 4; ++i)
        #pragma unroll
        for (int j = 0; j < 4; ++j)
            acc[i][j] = (int32x4){0,0,0,0};

    const int wo = (wave & 1) << 6;          // o half of wave tile
    const int wn = (wave >> 1) << 6;         // spatial half

    for (int kk = 0; kk < 9; ++kk) {
        const size_t kshift = (size_t)((kk/3)*WP_ + (kk%3))*16;   // pixel shift bytes
        const size_t aKK = (size_t)kk*16*4096;
        #pragma unroll
        for (int hf = 0; hf < 2; ++hf) {            // K halves: cq0 = 0, 8
            const int cq0 = hf*8;
            #pragma unroll
            for (int t = 0; t < 2; ++t) {
                const int kc = 2*wave + t;          // this wave's LDS chunks
                const int cq = cq0 + kc;
                const signed char* aG = qwT2 + aKK + (size_t)cq*4096;
                load16_lds(aG + aOff0, ldsA + kc*2048);
                load16_lds(aG + aOff1, ldsA + kc*2048 + 1024);
                const signed char* bG = qxp2 + (size_t)cq*PLANE_B + kshift;
                load16_lds(bG + bOff0, ldsB + kc*2048);
                load16_lds(bG + bOff1, ldsB + kc*2048 + 1024);
            }
            __syncthreads();
            #pragma unroll
            for (int ks = 0; ks < 2; ++ks) {
                const int ck = (ks*4 + quad)*2048;
                int32x4 af[4], bf[4];
                #pragma unroll
                for (int t = 0; t < 4; ++t) {
                    af[t] = *(const int32x4*)&ldsA[ck + (wo + t*16 + l15)*16];
                    bf[t] = *(const int32x4*)&ldsB[ck + (wn + t*16 + l15)*16];
                }
                #pragma unroll
                for (int mt = 0; mt < 4; ++mt)
                    #pragma unroll
                    for (int nt = 0; nt < 4; ++nt)
                        acc[mt][nt] = __builtin_amdgcn_mfma_i32_16x16x64_i8(
                            af[mt], bf[nt], acc[mt][nt], 0, 0, 0);
            }
            __syncthreads();
        }
    }

    // ---- epilogue: LDS transpose -> full-line float4 stores ----
    // pass p covers o_local in [p*64, p*64+64); written by waves with wo == p*64
    float* lt = (float*)smem;                      // [64][132] floats = 33792 B
    #pragma unroll
    for (int p = 0; p < 2; ++p) {
        __syncthreads();
        if ((wave & 1) == p) {
            #pragma unroll
            for (int mt = 0; mt < 4; ++mt)
                #pragma unroll
                for (int nt = 0; nt < 4; ++nt)
                    #pragma unroll
                    for (int r = 0; r < 4; ++r)
                        lt[(mt*16 + quad*4 + r)*132 + wn + nt*16 + l15]
                            = (float)acc[mt][nt][r];
        }
        __syncthreads();
        #pragma unroll
        for (int i = 0; i < 8; ++i) {
            int idx = i*256 + tid;                 // 2048 float4 chunks
            int o = idx >> 5;                      // 0..63
            int c = idx & 31;                      // sp/4 chunk
            float4 v = *(const float4*)&lt[o*132 + 4*c];
            int ol = p*64 + o;
            float is = invS[ol], bs = biasS[ol];
            unsigned sp = (unsigned)(s0 + 4*c);
            unsigned b  = sp / HW_;
            unsigned pos = sp - b*HW_;
            float4 wv;
            wv.x = fmaf(v.x, is, bs); wv.y = fmaf(v.y, is, bs);
            wv.z = fmaf(v.z, is, bs); wv.w = fmaf(v.w, is, bs);
            *(float4*)(out + (size_t)b*CHW_ + (size_t)(o0 + ol)*HW_ + pos) = wv;
        }
    }
}

extern "C" void kernel_launch(void* const* d_in, const int* in_sizes, int n_in,
                              void* d_out, int out_size, void* d_ws, size_t ws_size,
                              hipStream_t stream)
{
    (void)in_sizes; (void)n_in; (void)out_size; (void)ws_size;
    const float* x    = (const float*)d_in[0];
    const float* wgt  = (const float*)d_in[1];
    const float* bias = (const float*)d_in[2];
    const float* sw   = (const float*)d_in[3];
    const float* sx   = (const float*)d_in[4];
    float* out = (float*)d_out;

    signed char* qxp2 = (signed char*)d_ws;           // [cq][b][hp][wp][16]
    signed char* qwT2 = qxp2 + QXP_BYTES;             // [kk][cq][o][16]

    halo_rows_kernel<<<232, 256, 0, stream>>>(qxp2);
    quant_w_kernel<<<256, 256, 0, stream>>>(wgt, sw, qwT2);
    quant_x_kernel<<<1792, 256, 0, stream>>>(x, sx, qxp2);
    conv_kernel<<<dim3(784, 2), 256, 0, stream>>>(qxp2, qwT2, sw, bias, sx, out);
}